// Round 10
// baseline (1100.052 us; speedup 1.0000x reference)
//
#include <hip/hip_runtime.h>

// lstm_seq2seq fused persistent kernel for MI355X (gfx950), R10.
// ANTI-PHASE BATCH SPLIT: waves 0-3 = group A (rows 0-31), waves 4-7 =
// group B (rows 32-63). Groups are independent recurrences (batch rows
// independent; h buffers + flags group-local). Group B's MFMA(t) gates on
// group A's MFMA(t)-done flag -> half-step offset: on each SIMD one wave
// MFMAs while its partner does EW (m114 co-issue), breaking R8/R9's
// lock-step serialization of the MFMA and VALU phases.
// Cost: weight stream doubles to 1.15 MB/CU/step (~51 B/cyc sustained --
// the rate already measured in-window at R8).
// Carried: A=weights (L2, wl-packed), B=h (LDS), c in regs, decoder feedback
// folded, K=288 aug ("1" col = bias), log2e fold, kt=0 literal-zero C.
// Per wave: 16 i-tiles x 2 nt (acc = 128 AGPR, same shape as R4: no spill).

#define SEQ  20
#define TLEN 30
#define LOG2E  1.442695041f
#define LOG2E2 2.885390082f

typedef _Float16 half8   __attribute__((ext_vector_type(8)));
typedef _Float16 half4   __attribute__((ext_vector_type(4)));
typedef _Float16 half2v  __attribute__((ext_vector_type(2)));
typedef float    floatx4 __attribute__((ext_vector_type(4)));

// Packed weights. Gate row n (0..1023), k (0..287):
//   g=n>>8, c=(n>>4)&15, l16=n&15, wl=c>>2, cc=c&3, i=cc*4+g,
//   kt=k>>5, q=(k>>3)&3, j=k&7
//   dst = ((wl*9+kt)*16 + i)*512 + q*128 + l16*8 + j
// => per (wl,kt): 16 contiguous 1KB A-fragments. Waves w and w+4 share wl.
__device__ _Float16 g_w_enc[1024 * 288];
__device__ _Float16 g_w_dec0[1024 * 288];
__device__ _Float16 g_w_deff[1024 * 288];
__device__ _Float16 g_wout[512];           // W_out [2][256] f16 (unscaled)

__global__ void prep_kernel(const float* __restrict__ W_emb,
                            const float* __restrict__ b_emb,
                            const float* __restrict__ W_ih_enc,
                            const float* __restrict__ W_hh_enc,
                            const float* __restrict__ b_enc,
                            const float* __restrict__ W_ih_dec,
                            const float* __restrict__ W_hh_dec,
                            const float* __restrict__ b_dec,
                            const float* __restrict__ W_out,
                            const float* __restrict__ b_out) {
    int gid = blockIdx.x * blockDim.x + threadIdx.x;
    int stride = gridDim.x * blockDim.x;
    for (int s = gid; s < 1024 * 288; s += stride) {
        int n = s / 288, k = s - n * 288;
        int g = n >> 8, c = (n >> 4) & 15, l16 = n & 15;
        int wl = c >> 2, cc = c & 3;
        int i = cc * 4 + g;
        int kt = k >> 5, q = (k >> 3) & 3, j = k & 7;
        int dst = ((wl * 9 + kt) * 16 + i) * 512 + q * 128 + l16 * 8 + j;
        float sc = (g == 2) ? LOG2E2 : LOG2E;   // exp2-folded row scale
        float fe = 0.f, fd = 0.f, ff = 0.f;
        if (k < 256) {
            fe = W_hh_enc[n * 256 + k];
            fd = W_hh_dec[n * 256 + k];
            ff = fd + W_ih_dec[2 * n] * W_out[k]
                    + W_ih_dec[2 * n + 1] * W_out[256 + k];
        } else {
            int kp = k - 256;
            if (kp < 2) {
                fd = W_ih_dec[2 * n + kp];
                const float* wr = &W_ih_enc[n * 64];
                for (int e = 0; e < 64; e++) fe = fmaf(wr[e], W_emb[2 * e + kp], fe);
            } else if (kp == 2) {
                fd = b_dec[n];
                ff = b_dec[n] + W_ih_dec[2 * n] * b_out[0]
                              + W_ih_dec[2 * n + 1] * b_out[1];
                fe = b_enc[n];
                const float* wr = &W_ih_enc[n * 64];
                for (int e = 0; e < 64; e++) fe = fmaf(wr[e], b_emb[e], fe);
            }
        }
        g_w_enc[dst]  = (_Float16)(fe * sc);
        g_w_dec0[dst] = (_Float16)(fd * sc);
        g_w_deff[dst] = (_Float16)(ff * sc);
    }
    if (gid < 512) g_wout[gid] = (_Float16)W_out[gid];
}

__global__ __launch_bounds__(512, 2) void lstm_fused(
        const float* __restrict__ x_input,    // [20][16384][2]
        const float* __restrict__ b_out,      // [2]
        float* __restrict__ out)              // [30][16384][2]
{
    // h: [buf][nt(4)][kt(9)][512]; nt 0-1 = group A rows, nt 2-3 = group B.
    __shared__ __align__(16) _Float16 h_pack[2][18432];            // 73728 B
    __shared__ __align__(16) float    partial_lds[2][2][4 * 68];   // 8704 B
    __shared__ int hflag[2][4];   // [grp][wl]: h tiles 2wl,2wl+1 (+aug if wl0) done thru step v-1
    __shared__ int amf[2][4];     // [grp][wl]: MFMA phases completed
    __shared__ int cnt[2][2];     // out-proj arrival counters [grp][parity]

    const int tid = threadIdx.x;
    const int w   = tid >> 6;
    const int grp = w >> 2;        // 0 = rows 0-31, 1 = rows 32-63
    const int wl  = w & 3;         // wave-in-group; owns cells [64wl, 64wl+64)
    const int ntb = grp * 2;
    const int L   = tid & 63;
    const int l16 = L & 15;
    const int q   = L >> 4;
    const long row0 = (long)blockIdx.x * 64;

    // ---- init ----
    {
        int* hz = (int*)&h_pack[0][0];
        for (int idx = tid; idx < 18432; idx += 512) hz[idx] = 0;  // both bufs
        if (tid < 8)  hflag[tid >> 2][tid & 3] = 0;
        if (tid < 16 && tid >= 8) amf[(tid - 8) >> 2][tid & 3] = 0;
        if (tid < 20 && tid >= 16) cnt[(tid - 16) >> 1][tid & 1] = 0;
    }
    __syncthreads();
    if (tid < 128) {   // "1" column, both buffers, all 4 nt
        int buf = tid >> 6, b = tid & 63;
        h_pack[buf][((b >> 4) * 9 + 8) * 512 + (b & 15) * 8 + 2] = (_Float16)1.f;
    }
    if (tid < 128) {   // x(0) into buf0
        int b = tid >> 1, jj = tid & 1;
        h_pack[0][((b >> 4) * 9 + 8) * 512 + (b & 15) * 8 + jj] =
            (_Float16)x_input[(row0 + b) * 2 + jj];
    }

    const float boL = b_out[L & 1];
    const int aoff = q * 128 + l16 * 8;
    const _Float16* __restrict__ wenc_w  = &g_w_enc[wl * 73728];
    const _Float16* __restrict__ wdec0_w = &g_w_dec0[wl * 73728];
    const _Float16* __restrict__ wdeff_w = &g_w_deff[wl * 73728];

    _Float16 wo[2][4][4];   // [jj][cc][r] for cells 64wl+16cc+4q+r
#pragma unroll
    for (int jj = 0; jj < 2; jj++)
#pragma unroll
        for (int cc = 0; cc < 4; cc++)
#pragma unroll
            for (int r = 0; r < 4; r++)
                wo[jj][cc][r] = g_wout[jj * 256 + 64 * wl + 16 * cc + 4 * q + r];

    floatx4 acc[16][2];    // [i=cc*4+g][ntl]; D: gate row=4q+r, col=16nt+l16
    float   c_st[2][4][4]; // [ntl][cc][r]
#pragma unroll
    for (int ntl = 0; ntl < 2; ntl++)
#pragma unroll
        for (int cc = 0; cc < 4; cc++)
#pragma unroll
            for (int r = 0; r < 4; r++) c_st[ntl][cc][r] = 0.f;

    __syncthreads();   // the ONLY barrier

    auto ld32 = [&](int* p) {
        return __hip_atomic_load(p, __ATOMIC_RELAXED,
                                 __HIP_MEMORY_SCOPE_WORKGROUP);
    };

#pragma unroll 1
    for (int t = 0; t < SEQ + TLEN; t++) {
        const _Float16* __restrict__ Wb =
            (t < SEQ) ? wenc_w : (t == SEQ) ? wdec0_w : wdeff_w;
        const _Float16* __restrict__ hp = h_pack[t & 1];        // h(t-1)
        _Float16* __restrict__ hn = h_pack[(t + 1) & 1];        // h(t)

        // ---- phase gate (once per step) ----
        if (grp == 1) {
            // anti-phase: B's MFMA(t) starts only after A's MFMA(t) is done
            while (ld32(&amf[0][wl]) < t + 1) __builtin_amdgcn_s_sleep(1);
        } else {
            // soft anti-runaway: A stays within one step of B
            while (ld32(&amf[1][wl]) < t - 1) __builtin_amdgcn_s_sleep(1);
        }
        // own-group h(t-1) complete
        while (ld32(&hflag[grp][0]) < t || ld32(&hflag[grp][1]) < t ||
               ld32(&hflag[grp][2]) < t || ld32(&hflag[grp][3]) < t)
            __builtin_amdgcn_s_sleep(1);
        __builtin_amdgcn_sched_barrier(0);

        // ---- gates = [h|x|1] @ Waug^T (16 i-tiles x 2 nt); kt=0: C=0 ----
#pragma unroll
        for (int kt = 0; kt < 9; kt++) {
            half8 B0 = *(const half8*)&hp[(ntb * 9 + kt) * 512 + aoff];
            half8 B1 = *(const half8*)&hp[((ntb + 1) * 9 + kt) * 512 + aoff];
#pragma unroll
            for (int i = 0; i < 16; i++) {
                half8 Aw = *(const half8*)&Wb[(kt * 16 + i) * 512 + aoff];
                if (kt == 0) {
                    acc[i][0] = __builtin_amdgcn_mfma_f32_16x16x32_f16(
                        Aw, B0, (floatx4)(0.f), 0, 0, 0);
                    acc[i][1] = __builtin_amdgcn_mfma_f32_16x16x32_f16(
                        Aw, B1, (floatx4)(0.f), 0, 0, 0);
                } else {
                    acc[i][0] = __builtin_amdgcn_mfma_f32_16x16x32_f16(
                        Aw, B0, acc[i][0], 0, 0, 0);
                    acc[i][1] = __builtin_amdgcn_mfma_f32_16x16x32_f16(
                        Aw, B1, acc[i][1], 0, 0, 0);
                }
            }
        }

        // publish MFMA(t) done (scheduling gate only -> relaxed)
        if (L == 0)
            __hip_atomic_store(&amf[grp][wl], t + 1, __ATOMIC_RELAXED,
                               __HIP_MEMORY_SCOPE_WORKGROUP);

        // next-step x for this group's 32 rows (group's wave 0, lanes 0-31)
        float2 xv2 = make_float2(0.f, 0.f);
        if (wl == 0 && t < SEQ && L < 32) {
            int srct = (t + 1 < SEQ) ? t + 1 : SEQ - 1;
            xv2 = *(const float2*)
                &x_input[(long)srct * 32768 + (row0 + grp * 32 + L) * 2];
        }

        // ---- elementwise LSTM; h(f16)->hn; out-proj partials (decoder) ----
        const bool dec = (t >= SEQ);
        const int par = t & 1;
        float po[2][2];   // [ntl][jj]
        po[0][0] = 0.f; po[0][1] = 0.f; po[1][0] = 0.f; po[1][1] = 0.f;

#pragma unroll
        for (int ntl = 0; ntl < 2; ntl++)
#pragma unroll
            for (int cc = 0; cc < 4; cc++) {
                half4 hv4;
                float hvf[4];
#pragma unroll
                for (int r = 0; r < 4; r++) {
                    float ai = acc[cc * 4 + 0][ntl][r];
                    float af = acc[cc * 4 + 1][ntl][r];
                    float ag = acc[cc * 4 + 2][ntl][r];
                    float ao = acc[cc * 4 + 3][ntl][r];
                    float eI = __builtin_amdgcn_exp2f(-ai);
                    float eG = __builtin_amdgcn_exp2f(-ag);
                    float eF = __builtin_amdgcn_exp2f(-af);
                    float eO = __builtin_amdgcn_exp2f(-ao);
                    float ig = (1.f - eG) *
                        __builtin_amdgcn_rcpf((1.f + eI) * (1.f + eG));
                    float fs = __builtin_amdgcn_rcpf(1.f + eF);
                    float cn = fmaf(fs, c_st[ntl][cc][r], ig);
                    c_st[ntl][cc][r] = cn;
                    float cnc = fminf(fmaxf(cn, -12.f), 12.f);
                    float eC = __builtin_amdgcn_exp2f(-LOG2E2 * cnc);
                    float hv = (1.f - eC) *
                        __builtin_amdgcn_rcpf((1.f + eO) * (1.f + eC));
                    hvf[r] = hv;
                    hv4[r] = (_Float16)hv;
                }
                // cell = 64wl+16cc+4q+r -> kt2=2wl+(cc>>1), q2=2(cc&1)+(q>>1)
                *(half4*)&hn[((ntb + ntl) * 9 + 2 * wl + (cc >> 1)) * 512 +
                             (2 * (cc & 1) + (q >> 1)) * 128 +
                             l16 * 8 + 4 * (q & 1)] = hv4;
                if (dec) {
#pragma unroll
                    for (int r = 0; r < 4; r++) {
                        po[ntl][0] = fmaf(hvf[r], (float)wo[0][cc][r], po[ntl][0]);
                        po[ntl][1] = fmaf(hvf[r], (float)wo[1][cc][r], po[ntl][1]);
                    }
                }
            }

        // group's wave 0: x(t+1) into the aug tile of hn
        if (wl == 0 && t < SEQ && L < 32) {
            int b = grp * 32 + L;
            half2v xh; xh[0] = (_Float16)xv2.x; xh[1] = (_Float16)xv2.y;
            *(half2v*)&hn[((b >> 4) * 9 + 8) * 512 + (b & 15) * 8] = xh;
        }

        // publish this wave's h tiles (release drains the ds_writes)
        if (L == 0)
            __hip_atomic_store(&hflag[grp][wl], t + 1, __ATOMIC_RELEASE,
                               __HIP_MEMORY_SCOPE_WORKGROUP);

        // ---- decoder out-projection: group-local, counter-gated ----
        if (dec) {
#pragma unroll
            for (int ntl = 0; ntl < 2; ntl++)
#pragma unroll
                for (int jj = 0; jj < 2; jj++) {
                    float s = po[ntl][jj];
                    s += __shfl_xor(s, 16);
                    s += __shfl_xor(s, 32);
                    po[ntl][jj] = s;
                }
            if (q == 0) {
                float* pl = &partial_lds[grp][par][wl * 68];
#pragma unroll
                for (int ntl = 0; ntl < 2; ntl++) {
                    pl[ntl * 16 + l16]      = po[ntl][0];
                    pl[34 + ntl * 16 + l16] = po[ntl][1];
                }
            }
            __threadfence_block();
            int arr = 0;
            if (L == 0) arr = atomicAdd(&cnt[grp][par], 1);
            arr = __shfl(arr, 0);
            if (arr == 3) {    // 4th arrival in group finalizes 32 rows
                if (L == 0)
                    __hip_atomic_store(&cnt[grp][par], 0, __ATOMIC_RELAXED,
                                       __HIP_MEMORY_SCOPE_WORKGROUP);
                int r = L >> 1, jj = L & 1;
                float s = boL;
                const float* pl = &partial_lds[grp][par][jj * 34 + r];
#pragma unroll
                for (int w4 = 0; w4 < 4; w4++) s += pl[w4 * 68];
                out[(long)(t - SEQ) * 32768 + (row0 + grp * 32 + r) * 2 + jj] = s;
            }
        }
    }
}

extern "C" void kernel_launch(void* const* d_in, const int* in_sizes, int n_in,
                              void* d_out, int out_size, void* d_ws, size_t ws_size,
                              hipStream_t stream) {
    (void)in_sizes; (void)n_in; (void)d_ws; (void)ws_size; (void)out_size;
    const float* x      = (const float*)d_in[0];
    const float* W_emb  = (const float*)d_in[1];
    const float* b_emb  = (const float*)d_in[2];
    const float* W_ih_e = (const float*)d_in[3];
    const float* W_hh_e = (const float*)d_in[4];
    const float* b_enc  = (const float*)d_in[5];
    const float* W_ih_d = (const float*)d_in[6];
    const float* W_hh_d = (const float*)d_in[7];
    const float* b_dec  = (const float*)d_in[8];
    const float* W_out  = (const float*)d_in[9];
    const float* b_out  = (const float*)d_in[10];
    float* outp = (float*)d_out;

    prep_kernel<<<512, 256, 0, stream>>>(W_emb, b_emb, W_ih_e, W_hh_e, b_enc,
                                         W_ih_d, W_hh_d, b_dec, W_out, b_out);
    lstm_fused<<<256, 512, 0, stream>>>(x, b_out, outp);
}